// Round 1
// 419.290 us; speedup vs baseline: 1.0078x; 1.0078x over previous
//
#include <hip/hip_runtime.h>
#include <math.h>

// RoutingLayer fused via split-fp16 MFMA emulation of fp32 GEMM.
// routing = x@w_gate + noise*(softplus(x@w_noise)+0.01); out = scatter(softmax(top2)).
// x: 32768x2048 fp32, w_*: 2048x64 fp32, noise: 32768x64, out: 32768x64.
//
// R5: latency-bound fix. Previous version staged x through LDS with a
// vmcnt-draining __syncthreads per chunk (depth-1 pipeline => full HBM
// latency on every chunk; MfmaUtil 12%, VALUBusy 19%, HBM 11%).
// Now:
//  - A-fragments load DIRECTLY global->registers per lane (frag layout
//    A[m=lane&15][k=q*8+j] = 2 contiguous float4/mtile), register
//    double-buffered; fp32->fp16-split conversion happens in VALU from regs.
//    The wnh-twin wave's duplicate read is an L1/L2 hit (same CU, same time).
//  - B stays global_load_lds, but QUAD-buffered (64 KB LDS) with ONE raw
//    s_barrier + counted s_waitcnt vmcnt(8) per chunk (never drains; the
//    next chunk's 8-op batch stays in flight across the barrier).
//  - Loop unrolled x4 so buffer/reg-select indices are compile-time.
//  - All LDS accesses lane-linear 16B => zero bank conflicts.

typedef _Float16 half4v __attribute__((ext_vector_type(4)));
typedef _Float16 half8v __attribute__((ext_vector_type(8)));
typedef float f32x4 __attribute__((ext_vector_type(4)));

constexpr int DIMK = 2048;
constexpr int NEXP = 64;
constexpr int BM   = 64;         // rows per block
constexpr int NCH  = DIMK / 32;  // 64 k-chunks of 32

__device__ __forceinline__ void async_load16(const void* g, void* l) {
    // global -> LDS DMA, 16B/lane; LDS dest = uniform base + lane*16
    __builtin_amdgcn_global_load_lds(
        (const __attribute__((address_space(1))) unsigned int*)g,
        (__attribute__((address_space(3))) unsigned int*)l, 16, 0, 0);
}

__device__ __forceinline__ bool gt_pair(float a, int ia, float b, int ib) {
    return (a > b) || (a == b && ia < ib);   // jax top_k: lower index wins ties
}

// ---- pre-kernel: split w' = 65536*[wg|wn] into 2 fp16 planes in B-frag order.
// ws layout: [chunk c][plane p][ntile t][lane][8 halfs]  (1KB per (c,p,t))
// B-frag (16x16x32): lane holds B[k = c*32 + (lane>>4)*8 + j][n = t*16 + (lane&15)]
__global__ __launch_bounds__(256)
void presplit_kernel(const float* __restrict__ wg, const float* __restrict__ wn,
                     _Float16* __restrict__ wsB)
{
    int gid  = blockIdx.x * 256 + threadIdx.x;   // 0..32767 = (c, t, lane)
    int lane = gid & 63;
    int t    = (gid >> 6) & 7;
    int c    = gid >> 9;
    int n    = t * 16 + (lane & 15);
    int kb   = c * 32 + ((lane >> 4) << 3);
    const float* src = (n < NEXP) ? (wg + n) : (wn + (n - NEXP));
    half8v h1, h2;
    #pragma unroll
    for (int j = 0; j < 8; ++j) {
        float w = src[(size_t)(kb + j) * NEXP] * 65536.0f;
        _Float16 a = (_Float16)w;
        h1[j] = a;
        h2[j] = (_Float16)(w - (float)a);
    }
    *(half8v*)(wsB + ((((size_t)c * 2 + 0) * 8 + t) * 64 + lane) * 8) = h1;
    *(half8v*)(wsB + ((((size_t)c * 2 + 1) * 8 + t) * 64 + lane) * 8) = h2;
}

// ---- main kernel: 256 threads = 4 waves as (wm = row-half, wnh = expert-half).
// Wave tile: 32 rows x [16+16 gate cols | matching 16+16 noise cols].
__global__ __launch_bounds__(256)
void routing_mfma(const float* __restrict__ x, const _Float16* __restrict__ wsB,
                  const float* __restrict__ noise, float* __restrict__ out)
{
    __shared__ _Float16 Bp[4][2][8][64][8];   // 64 KB: quad-buffered B frags
    __shared__ float4   cand[BM][2];          // 2 KB
    __shared__ float4   res[BM];              // 1 KB

    const int tid  = threadIdx.x;
    const int lane = tid & 63;
    const int w    = tid >> 6;
    const int wm   = w >> 1;            // row half (0,1)
    const int wnh  = w & 1;             // expert half (0,1)
    const int q    = lane >> 4;
    const int cidx = lane & 15;
    const int row0 = blockIdx.x * BM;

    f32x4  acc[2][4] = {};              // [mt][tt: 0,1=gate tiles, 2,3=noise tiles]
    float4 ra[2][4];                    // raw A double-buffer (SEL is always literal)

    // A-frag source rows: lane (m=cidx) of mtile 0/1, k-offset q*8
    const float* xr0 = x + (size_t)(row0 + wm * 32 + cidx) * DIMK + q * 8;
    const float* xr1 = xr0 + 16 * DIMK;

    auto issue_B = [&](int c, int buf) {
        #pragma unroll
        for (int ii = 0; ii < 4; ++ii) {          // 16 (p,t) frag blocks / block
            int idx = w * 4 + ii;
            int p = idx >> 3, t = idx & 7;
            const _Float16* g = wsB + ((((size_t)c * 2 + p) * 8 + t) * 64 + lane) * 8;
            async_load16(g, &Bp[buf][p][t][0][0]);
        }
    };

#define ISSUE_A(C, S)                                            \
    {   const float* pa_ = xr0 + (C) * 32;                       \
        const float* pb_ = xr1 + (C) * 32;                       \
        ra[S][0] = *(const float4*)(pa_);                        \
        ra[S][1] = *(const float4*)(pa_ + 4);                    \
        ra[S][2] = *(const float4*)(pb_);                        \
        ra[S][3] = *(const float4*)(pb_ + 4);  }

#define FENCE() asm volatile("" ::: "memory")

    // One chunk. Exactly 8 VMEM ops issued per thread per STEP (4 gll + 4
    // float4), fence-separated => vmcnt(8) at the top retires chunk C's
    // batch while chunk C+1's batch stays in flight across the barrier.
#define STEP(C, BUF, NBUF, SEL, ISS, WN)                                     \
    {                                                                        \
        asm volatile("s_waitcnt vmcnt(" #WN ")" ::: "memory");               \
        asm volatile("s_barrier" ::: "memory");                              \
        if (ISS) issue_B((C) + 2, NBUF);                                     \
        half8v af[2][2];                                                     \
        _Pragma("unroll")                                                    \
        for (int mt = 0; mt < 2; ++mt) {                                     \
            _Pragma("unroll")                                                \
            for (int h = 0; h < 2; ++h) {                                    \
                float4 v = ra[SEL][mt * 2 + h];                              \
                float f0 = v.x * 1024.f, f1 = v.y * 1024.f;                  \
                float f2 = v.z * 1024.f, f3 = v.w * 1024.f;                  \
                _Float16 a0 = (_Float16)f0, a1 = (_Float16)f1;               \
                _Float16 a2 = (_Float16)f2, a3 = (_Float16)f3;               \
                af[mt][0][h * 4 + 0] = a0;                                   \
                af[mt][0][h * 4 + 1] = a1;                                   \
                af[mt][0][h * 4 + 2] = a2;                                   \
                af[mt][0][h * 4 + 3] = a3;                                   \
                af[mt][1][h * 4 + 0] = (_Float16)(f0 - (float)a0);           \
                af[mt][1][h * 4 + 1] = (_Float16)(f1 - (float)a1);           \
                af[mt][1][h * 4 + 2] = (_Float16)(f2 - (float)a2);           \
                af[mt][1][h * 4 + 3] = (_Float16)(f3 - (float)a3);           \
            }                                                                \
        }                                                                    \
        if (ISS) ISSUE_A((C) + 2, SEL);                                      \
        half8v bf[4][2];                                                     \
        _Pragma("unroll")                                                    \
        for (int tt = 0; tt < 4; ++tt) {                                     \
            int ntile = (tt < 2) ? (wnh * 2 + tt) : (4 + wnh * 2 + (tt - 2));\
            _Pragma("unroll")                                                \
            for (int p = 0; p < 2; ++p)                                      \
                bf[tt][p] = *(const half8v*)&Bp[BUF][p][ntile][lane][0];     \
        }                                                                    \
        _Pragma("unroll")                                                    \
        for (int mt = 0; mt < 2; ++mt) {                                     \
            _Pragma("unroll")                                                \
            for (int tt = 0; tt < 4; ++tt) {                                 \
                acc[mt][tt] = __builtin_amdgcn_mfma_f32_16x16x32_f16(        \
                    af[mt][0], bf[tt][0], acc[mt][tt], 0, 0, 0);             \
                acc[mt][tt] = __builtin_amdgcn_mfma_f32_16x16x32_f16(        \
                    af[mt][0], bf[tt][1], acc[mt][tt], 0, 0, 0);             \
                acc[mt][tt] = __builtin_amdgcn_mfma_f32_16x16x32_f16(        \
                    af[mt][1], bf[tt][0], acc[mt][tt], 0, 0, 0);             \
            }                                                                \
        }                                                                    \
    }

    // Prologue: batches 0 and 1 (fence keeps batch issue-order for vmcnt math)
    issue_B(0, 0);
    ISSUE_A(0, 0);
    FENCE();
    issue_B(1, 1);
    ISSUE_A(1, 1);

    #pragma unroll 1
    for (int cb = 0; cb < NCH - 4; cb += 4) {
        STEP(cb + 0, 0, 2, 0, 1, 8)
        STEP(cb + 1, 1, 3, 1, 1, 8)
        STEP(cb + 2, 2, 0, 0, 1, 8)
        STEP(cb + 3, 3, 1, 1, 1, 8)
    }
    // Tail: chunks 60..63 (prefetch tapers off; only the last step drains)
    STEP(NCH - 4, 0, 2, 0, 1, 8)
    STEP(NCH - 3, 1, 3, 1, 1, 8)
    STEP(NCH - 2, 2, 0, 0, 0, 8)
    STEP(NCH - 1, 3, 0, 1, 0, 0)

#undef STEP
#undef ISSUE_A
#undef FENCE

    // ---- epilogue ----
    // C/D layout: col = lane&15, row = q*4 + reg. Unscale by 2^-26 (1024*65536).
    const float s = 0x1p-26f;
    #pragma unroll
    for (int mt = 0; mt < 2; ++mt) {
        float rv[2][4];
        #pragma unroll
        for (int g = 0; g < 2; ++g) {
            int e     = wnh * 32 + g * 16 + cidx;
            int rbase = row0 + wm * 32 + mt * 16 + q * 4;
            #pragma unroll
            for (int r = 0; r < 4; ++r) {
                float nz   = noise[(size_t)(rbase + r) * NEXP + e];
                float gate = acc[mt][g][r] * s;
                float nv   = acc[mt][g + 2][r] * s;
                float sp   = fmaxf(nv, 0.f) + log1pf(expf(-fabsf(nv)));
                rv[g][r]   = gate + nz * (sp + 0.01f);
            }
        }
        #pragma unroll
        for (int r = 0; r < 4; ++r) {
            int e0 = wnh * 32 + cidx, e1 = e0 + 16;
            float v1, v2; int i1, i2;
            float a = rv[0][r], b = rv[1][r];
            if (a >= b) { v1 = a; i1 = e0; v2 = b; i2 = e1; }   // e0<e1: tie ok
            else        { v1 = b; i1 = e1; v2 = a; i2 = e0; }
            #pragma unroll
            for (int m = 1; m <= 8; m <<= 1) {    // butterfly across the 16-lane quad
                float b1 = __shfl_xor(v1, m); int ib1 = __shfl_xor(i1, m);
                float b2 = __shfl_xor(v2, m); int ib2 = __shfl_xor(i2, m);
                if (gt_pair(b1, ib1, v1, i1)) {
                    float o1 = v1; int oi1 = i1;
                    v1 = b1; i1 = ib1;
                    if (gt_pair(b2, ib2, o1, oi1)) { v2 = b2; i2 = ib2; }
                    else                           { v2 = o1; i2 = oi1; }
                } else if (gt_pair(b1, ib1, v2, i2)) {
                    v2 = b1; i2 = ib1;
                }
            }
            if (cidx == 0) {
                int rowb = wm * 32 + mt * 16 + q * 4 + r;
                cand[rowb][wnh] = make_float4(v1, __int_as_float(i1),
                                              v2, __int_as_float(i2));
            }
        }
    }
    __syncthreads();

    if (tid < BM) {   // merge the two expert-half candidates, softmax
        float4 c0 = cand[tid][0], c1 = cand[tid][1];
        float mv1 = c0.x; int mi1 = __float_as_int(c0.y);
        float mv2 = c0.z; int mi2 = __float_as_int(c0.w);
        float b1 = c1.x;  int ib1 = __float_as_int(c1.y);
        float b2 = c1.z;  int ib2 = __float_as_int(c1.w);
        if (gt_pair(b1, ib1, mv1, mi1)) {
            float o1 = mv1; int oi1 = mi1;
            mv1 = b1; mi1 = ib1;
            if (gt_pair(b2, ib2, o1, oi1)) { mv2 = b2; mi2 = ib2; }
            else                           { mv2 = o1; mi2 = oi1; }
        } else if (gt_pair(b1, ib1, mv2, mi2)) {
            mv2 = b1; mi2 = ib1;
        }
        float t  = expf(mv2 - mv1);     // <= 1
        float g1 = 1.f / (1.f + t);
        res[tid] = make_float4(g1, __int_as_float(mi1),
                               t * g1, __int_as_float(mi2));
    }
    __syncthreads();

    {   // write full 64x64 out tile: thread -> row tid>>2, 16-col segment
        int rr  = tid >> 2;
        int seg = tid & 3;
        float4 rv = res[rr];
        float g1 = rv.x, g2 = rv.z;
        int   j1 = __float_as_int(rv.y), j2 = __float_as_int(rv.w);
        float* op = out + (size_t)(row0 + rr) * NEXP + seg * 16;
        #pragma unroll
        for (int qq = 0; qq < 4; ++qq) {
            int e0 = seg * 16 + qq * 4;
            float4 o;
            o.x = (e0 + 0 == j1) ? g1 : ((e0 + 0 == j2) ? g2 : 0.f);
            o.y = (e0 + 1 == j1) ? g1 : ((e0 + 1 == j2) ? g2 : 0.f);
            o.z = (e0 + 2 == j1) ? g1 : ((e0 + 2 == j2) ? g2 : 0.f);
            o.w = (e0 + 3 == j1) ? g1 : ((e0 + 3 == j2) ? g2 : 0.f);
            *(float4*)(op + qq * 4) = o;
        }
    }
}

extern "C" void kernel_launch(void* const* d_in, const int* in_sizes, int n_in,
                              void* d_out, int out_size, void* d_ws, size_t ws_size,
                              hipStream_t stream) {
    const float* x     = (const float*)d_in[0];
    const float* wg    = (const float*)d_in[1];
    const float* wn    = (const float*)d_in[2];
    const float* noise = (const float*)d_in[3];
    float* out = (float*)d_out;
    _Float16* wsB = (_Float16*)d_ws;   // needs 64*2*8*1KB = 1 MB

    presplit_kernel<<<dim3(128), 256, 0, stream>>>(wg, wn, wsB);

    const int Brows = in_sizes[0] / DIMK;          // 32768
    dim3 grid(Brows / BM);                         // 512 blocks -> 2/CU
    routing_mfma<<<grid, 256, 0, stream>>>(x, wsB, noise, out);
}

// Round 2
// 403.330 us; speedup vs baseline: 1.0477x; 1.0396x over previous
//
#include <hip/hip_runtime.h>
#include <math.h>

// RoutingLayer fused via split-fp16 MFMA emulation of fp32 GEMM.
// routing = x@w_gate + noise*(softplus(x@w_noise)+0.01); out = scatter(softmax(top2)).
// x: 32768x2048 fp32, w_*: 2048x64 fp32, noise: 32768x64, out: 32768x64.
//
// R6: occupancy fix. R5's counted-vmcnt restructure didn't move perf
// (166->160us): the shared bottleneck was 8 waves/CU (2/SIMD) -- every
// latency bubble idled the SIMD. Now 512-thread blocks (8 waves: 4 mtiles
// x 2 expert-halves), same 67 KB LDS -> 2 blocks/CU -> 16 waves/CU,
// 4 waves/SIMD. Per-wave step work halves (12 MFMA, 4 VMEM ops), and the
// quad-buffered B enables depth-3 prefetch: vmcnt(8) retires batch C with
// C+1..C+3 in flight. __launch_bounds__(512,4) caps VGPR<=128.

typedef _Float16 half4v __attribute__((ext_vector_type(4)));
typedef _Float16 half8v __attribute__((ext_vector_type(8)));
typedef float f32x4 __attribute__((ext_vector_type(4)));

constexpr int DIMK = 2048;
constexpr int NEXP = 64;
constexpr int BM   = 64;         // rows per block
constexpr int NCH  = DIMK / 32;  // 64 k-chunks of 32

__device__ __forceinline__ void async_load16(const void* g, void* l) {
    // global -> LDS DMA, 16B/lane; LDS dest = uniform base + lane*16
    __builtin_amdgcn_global_load_lds(
        (const __attribute__((address_space(1))) unsigned int*)g,
        (__attribute__((address_space(3))) unsigned int*)l, 16, 0, 0);
}

__device__ __forceinline__ bool gt_pair(float a, int ia, float b, int ib) {
    return (a > b) || (a == b && ia < ib);   // jax top_k: lower index wins ties
}

// ---- pre-kernel: split w' = 65536*[wg|wn] into 2 fp16 planes in B-frag order.
// ws layout: [chunk c][plane p][ntile t][lane][8 halfs]  (1KB per (c,p,t))
// B-frag (16x16x32): lane holds B[k = c*32 + (lane>>4)*8 + j][n = t*16 + (lane&15)]
__global__ __launch_bounds__(256)
void presplit_kernel(const float* __restrict__ wg, const float* __restrict__ wn,
                     _Float16* __restrict__ wsB)
{
    int gid  = blockIdx.x * 256 + threadIdx.x;   // 0..32767 = (c, t, lane)
    int lane = gid & 63;
    int t    = (gid >> 6) & 7;
    int c    = gid >> 9;
    int n    = t * 16 + (lane & 15);
    int kb   = c * 32 + ((lane >> 4) << 3);
    const float* src = (n < NEXP) ? (wg + n) : (wn + (n - NEXP));
    half8v h1, h2;
    #pragma unroll
    for (int j = 0; j < 8; ++j) {
        float w = src[(size_t)(kb + j) * NEXP] * 65536.0f;
        _Float16 a = (_Float16)w;
        h1[j] = a;
        h2[j] = (_Float16)(w - (float)a);
    }
    *(half8v*)(wsB + ((((size_t)c * 2 + 0) * 8 + t) * 64 + lane) * 8) = h1;
    *(half8v*)(wsB + ((((size_t)c * 2 + 1) * 8 + t) * 64 + lane) * 8) = h2;
}

// ---- main kernel: 512 threads = 8 waves as (mt = mtile 0..3, wnh = expert half).
// Wave tile: 16 rows x [16+16 gate cols | matching 16+16 noise cols].
__global__ __launch_bounds__(512, 4)
void routing_mfma(const float* __restrict__ x, const _Float16* __restrict__ wsB,
                  const float* __restrict__ noise, float* __restrict__ out)
{
    __shared__ _Float16 Bp[4][2][8][64][8];   // 64 KB: quad-buffered B frags
    __shared__ float4   cand[BM][2];          // 2 KB
    __shared__ float4   res[BM];              // 1 KB

    const int tid  = threadIdx.x;
    const int lane = tid & 63;
    const int w    = tid >> 6;          // 0..7
    const int mt   = w >> 1;            // mtile (0..3): rows mt*16..mt*16+15
    const int wnh  = w & 1;             // expert half (0,1)
    const int q    = lane >> 4;
    const int cidx = lane & 15;
    const int row0 = blockIdx.x * BM;

    f32x4  acc[4] = {};                 // [tt: 0,1=gate tiles, 2,3=noise tiles]
    float4 ra[4][2];                    // raw A quad-buffer (slot index always literal)

    // A-frag source row: lane (m=cidx) of this wave's mtile, k-offset q*8
    const float* xr0 = x + (size_t)(row0 + mt * 16 + cidx) * DIMK + q * 8;

    auto issue_B = [&](int c, int buf) {
        #pragma unroll
        for (int ii = 0; ii < 2; ++ii) {          // 16 (p,t) frag blocks / block
            int idx = w * 2 + ii;
            int p = idx >> 3, t = idx & 7;
            const _Float16* g = wsB + ((((size_t)c * 2 + p) * 8 + t) * 64 + lane) * 8;
            async_load16(g, &Bp[buf][p][t][0][0]);
        }
    };

#define ISSUE_A(C, S)                                            \
    {   const float* pa_ = xr0 + (C) * 32;                       \
        ra[S][0] = *(const float4*)(pa_);                        \
        ra[S][1] = *(const float4*)(pa_ + 4);  }

#define FENCE() asm volatile("" ::: "memory")

    // One chunk. Exactly 4 VMEM ops per thread per STEP (2 DMA + 2 float4),
    // batch-contiguous => vmcnt(8) at the top retires batch C while
    // C+1..C+3 (12 -> 8 after wait) stay in flight across the barrier.
#define STEP(C, ISS, WN)                                                     \
    {                                                                        \
        asm volatile("s_waitcnt vmcnt(" #WN ")" ::: "memory");               \
        asm volatile("s_barrier" ::: "memory");                              \
        if (ISS) issue_B((C) + 3, ((C) + 3) & 3);                            \
        half8v af0, af1;                                                     \
        _Pragma("unroll")                                                    \
        for (int h = 0; h < 2; ++h) {                                        \
            float4 v = ra[(C) & 3][h];                                       \
            float f0 = v.x * 1024.f, f1 = v.y * 1024.f;                      \
            float f2 = v.z * 1024.f, f3 = v.w * 1024.f;                      \
            _Float16 a0 = (_Float16)f0, a1 = (_Float16)f1;                   \
            _Float16 a2 = (_Float16)f2, a3 = (_Float16)f3;                   \
            af0[h * 4 + 0] = a0; af0[h * 4 + 1] = a1;                        \
            af0[h * 4 + 2] = a2; af0[h * 4 + 3] = a3;                        \
            af1[h * 4 + 0] = (_Float16)(f0 - (float)a0);                     \
            af1[h * 4 + 1] = (_Float16)(f1 - (float)a1);                     \
            af1[h * 4 + 2] = (_Float16)(f2 - (float)a2);                     \
            af1[h * 4 + 3] = (_Float16)(f3 - (float)a3);                     \
        }                                                                    \
        if (ISS) ISSUE_A((C) + 3, ((C) + 3) & 3);                            \
        __builtin_amdgcn_s_setprio(1);                                       \
        _Pragma("unroll")                                                    \
        for (int tt = 0; tt < 4; ++tt) {                                     \
            int ntile = (tt < 2) ? (wnh * 2 + tt) : (4 + wnh * 2 + (tt - 2));\
            half8v b0 = *(const half8v*)&Bp[(C) & 3][0][ntile][lane][0];     \
            half8v b1 = *(const half8v*)&Bp[(C) & 3][1][ntile][lane][0];     \
            acc[tt] = __builtin_amdgcn_mfma_f32_16x16x32_f16(                \
                af0, b0, acc[tt], 0, 0, 0);                                  \
            acc[tt] = __builtin_amdgcn_mfma_f32_16x16x32_f16(                \
                af0, b1, acc[tt], 0, 0, 0);                                  \
            acc[tt] = __builtin_amdgcn_mfma_f32_16x16x32_f16(                \
                af1, b0, acc[tt], 0, 0, 0);                                  \
        }                                                                    \
        __builtin_amdgcn_s_setprio(0);                                       \
    }

    // Prologue: batches 0..2 (fences keep batch issue-order for vmcnt math)
    issue_B(0, 0);
    ISSUE_A(0, 0);
    FENCE();
    issue_B(1, 1);
    ISSUE_A(1, 1);
    FENCE();
    issue_B(2, 2);
    ISSUE_A(2, 2);

    #pragma unroll 1
    for (int cb = 0; cb < NCH - 4; cb += 4) {
        STEP(cb + 0, 1, 8)
        STEP(cb + 1, 1, 8)
        STEP(cb + 2, 1, 8)
        STEP(cb + 3, 1, 8)
    }
    // Tail: chunks 60..63 (C=60 issues batch 63; then prefetch tapers off)
    STEP(NCH - 4, 1, 8)
    STEP(NCH - 3, 0, 8)
    STEP(NCH - 2, 0, 4)
    STEP(NCH - 1, 0, 0)

#undef STEP
#undef ISSUE_A
#undef FENCE

    // ---- epilogue ----
    // C/D layout: col = lane&15, row = q*4 + reg. Unscale by 2^-26 (1024*65536).
    const float s = 0x1p-26f;
    {
        float rv[2][4];
        const int rbase = row0 + mt * 16 + q * 4;
        #pragma unroll
        for (int g = 0; g < 2; ++g) {
            int e = wnh * 32 + g * 16 + cidx;
            #pragma unroll
            for (int r = 0; r < 4; ++r) {
                float nz   = noise[(size_t)(rbase + r) * NEXP + e];
                float gate = acc[g][r] * s;
                float nv   = acc[g + 2][r] * s;
                float sp   = fmaxf(nv, 0.f) + log1pf(expf(-fabsf(nv)));
                rv[g][r]   = gate + nz * (sp + 0.01f);
            }
        }
        #pragma unroll
        for (int r = 0; r < 4; ++r) {
            int e0 = wnh * 32 + cidx, e1 = e0 + 16;
            float v1, v2; int i1, i2;
            float a = rv[0][r], b = rv[1][r];
            if (a >= b) { v1 = a; i1 = e0; v2 = b; i2 = e1; }   // e0<e1: tie ok
            else        { v1 = b; i1 = e1; v2 = a; i2 = e0; }
            #pragma unroll
            for (int m = 1; m <= 8; m <<= 1) {    // butterfly across the 16-lane quad
                float b1 = __shfl_xor(v1, m); int ib1 = __shfl_xor(i1, m);
                float b2 = __shfl_xor(v2, m); int ib2 = __shfl_xor(i2, m);
                if (gt_pair(b1, ib1, v1, i1)) {
                    float o1 = v1; int oi1 = i1;
                    v1 = b1; i1 = ib1;
                    if (gt_pair(b2, ib2, o1, oi1)) { v2 = b2; i2 = ib2; }
                    else                           { v2 = o1; i2 = oi1; }
                } else if (gt_pair(b1, ib1, v2, i2)) {
                    v2 = b1; i2 = ib1;
                }
            }
            if (cidx == 0) {
                int rowb = mt * 16 + q * 4 + r;
                cand[rowb][wnh] = make_float4(v1, __int_as_float(i1),
                                              v2, __int_as_float(i2));
            }
        }
    }
    __syncthreads();

    if (tid < BM) {   // merge the two expert-half candidates, softmax
        float4 c0 = cand[tid][0], c1 = cand[tid][1];
        float mv1 = c0.x; int mi1 = __float_as_int(c0.y);
        float mv2 = c0.z; int mi2 = __float_as_int(c0.w);
        float b1 = c1.x;  int ib1 = __float_as_int(c1.y);
        float b2 = c1.z;  int ib2 = __float_as_int(c1.w);
        if (gt_pair(b1, ib1, mv1, mi1)) {
            float o1 = mv1; int oi1 = mi1;
            mv1 = b1; mi1 = ib1;
            if (gt_pair(b2, ib2, o1, oi1)) { mv2 = b2; mi2 = ib2; }
            else                           { mv2 = o1; mi2 = oi1; }
        } else if (gt_pair(b1, ib1, mv2, mi2)) {
            mv2 = b1; mi2 = ib1;
        }
        float t  = expf(mv2 - mv1);     // <= 1
        float g1 = 1.f / (1.f + t);
        res[tid] = make_float4(g1, __int_as_float(mi1),
                               t * g1, __int_as_float(mi2));
    }
    __syncthreads();

    {   // write full 64x64 out tile: thread -> row tid>>3, 8-col segment
        int rr  = tid >> 3;          // 0..63
        int seg = tid & 7;           // 0..7
        float4 rv = res[rr];
        float g1 = rv.x, g2 = rv.z;
        int   j1 = __float_as_int(rv.y), j2 = __float_as_int(rv.w);
        float* op = out + (size_t)(row0 + rr) * NEXP + seg * 8;
        #pragma unroll
        for (int qq = 0; qq < 2; ++qq) {
            int e0 = seg * 8 + qq * 4;
            float4 o;
            o.x = (e0 + 0 == j1) ? g1 : ((e0 + 0 == j2) ? g2 : 0.f);
            o.y = (e0 + 1 == j1) ? g1 : ((e0 + 1 == j2) ? g2 : 0.f);
            o.z = (e0 + 2 == j1) ? g1 : ((e0 + 2 == j2) ? g2 : 0.f);
            o.w = (e0 + 3 == j1) ? g1 : ((e0 + 3 == j2) ? g2 : 0.f);
            *(float4*)(op + qq * 4) = o;
        }
    }
}

extern "C" void kernel_launch(void* const* d_in, const int* in_sizes, int n_in,
                              void* d_out, int out_size, void* d_ws, size_t ws_size,
                              hipStream_t stream) {
    const float* x     = (const float*)d_in[0];
    const float* wg    = (const float*)d_in[1];
    const float* wn    = (const float*)d_in[2];
    const float* noise = (const float*)d_in[3];
    float* out = (float*)d_out;
    _Float16* wsB = (_Float16*)d_ws;   // needs 64*2*8*1KB = 1 MB

    presplit_kernel<<<dim3(128), 256, 0, stream>>>(wg, wn, wsB);

    const int Brows = in_sizes[0] / DIMK;          // 32768
    dim3 grid(Brows / BM);                         // 512 blocks -> 2/CU, 16 waves/CU
    routing_mfma<<<grid, 512, 0, stream>>>(x, wsB, noise, out);
}

// Round 4
// 403.024 us; speedup vs baseline: 1.0485x; 1.0008x over previous
//
#include <hip/hip_runtime.h>
#include <math.h>

// RoutingLayer fused via split-fp16 MFMA emulation of fp32 GEMM.
// routing = x@w_gate + noise*(softplus(x@w_noise)+0.01); out = scatter(softmax(top2)).
// x: 32768x2048 fp32, w_*: 2048x64 fp32, noise: 32768x64, out: 32768x64.
//
// R7 (resubmit; previous round was an infra failure, not a kernel error).
// Phase-overlap fix. R6 (16 waves/CU) only gained 9% over 8 waves/CU:
// per-step barrier locksteps all waves into the same [VMEM][convert][MFMA]
// phase, and the convert->MFMA dependency serializes each step. Pipe-sum
// accounting (VMEM ~27us + LDS ~40us + VALU ~30us + MFMA ~25us) matches the
// measured 146us => near-zero overlap. Now the A-convert runs ONE CHUNK
// AHEAD into a double-buffered af[] pair: step C's MFMAs consume af[C&1]
// (ready at barrier), then convert(C+1) fills af[(C+1)&1] with no MFMA
// dependency -> VALU slides under the MFMA/LDS pipes, waves de-phase.
// VMEM batch order per step unchanged ([2 gll][2 ra]) => vmcnt math intact.

typedef _Float16 half4v __attribute__((ext_vector_type(4)));
typedef _Float16 half8v __attribute__((ext_vector_type(8)));
typedef float f32x4 __attribute__((ext_vector_type(4)));

constexpr int DIMK = 2048;
constexpr int NEXP = 64;
constexpr int BM   = 64;         // rows per block
constexpr int NCH  = DIMK / 32;  // 64 k-chunks of 32

__device__ __forceinline__ void async_load16(const void* g, void* l) {
    // global -> LDS DMA, 16B/lane; LDS dest = uniform base + lane*16
    __builtin_amdgcn_global_load_lds(
        (const __attribute__((address_space(1))) unsigned int*)g,
        (__attribute__((address_space(3))) unsigned int*)l, 16, 0, 0);
}

__device__ __forceinline__ bool gt_pair(float a, int ia, float b, int ib) {
    return (a > b) || (a == b && ia < ib);   // jax top_k: lower index wins ties
}

// ---- pre-kernel: split w' = 65536*[wg|wn] into 2 fp16 planes in B-frag order.
// ws layout: [chunk c][plane p][ntile t][lane][8 halfs]  (1KB per (c,p,t))
// B-frag (16x16x32): lane holds B[k = c*32 + (lane>>4)*8 + j][n = t*16 + (lane&15)]
__global__ __launch_bounds__(256)
void presplit_kernel(const float* __restrict__ wg, const float* __restrict__ wn,
                     _Float16* __restrict__ wsB)
{
    int gid  = blockIdx.x * 256 + threadIdx.x;   // 0..32767 = (c, t, lane)
    int lane = gid & 63;
    int t    = (gid >> 6) & 7;
    int c    = gid >> 9;
    int n    = t * 16 + (lane & 15);
    int kb   = c * 32 + ((lane >> 4) << 3);
    const float* src = (n < NEXP) ? (wg + n) : (wn + (n - NEXP));
    half8v h1, h2;
    #pragma unroll
    for (int j = 0; j < 8; ++j) {
        float w = src[(size_t)(kb + j) * NEXP] * 65536.0f;
        _Float16 a = (_Float16)w;
        h1[j] = a;
        h2[j] = (_Float16)(w - (float)a);
    }
    *(half8v*)(wsB + ((((size_t)c * 2 + 0) * 8 + t) * 64 + lane) * 8) = h1;
    *(half8v*)(wsB + ((((size_t)c * 2 + 1) * 8 + t) * 64 + lane) * 8) = h2;
}

// ---- main kernel: 512 threads = 8 waves as (mt = mtile 0..3, wnh = expert half).
// Wave tile: 16 rows x [16+16 gate cols | matching 16+16 noise cols].
__global__ __launch_bounds__(512, 4)
void routing_mfma(const float* __restrict__ x, const _Float16* __restrict__ wsB,
                  const float* __restrict__ noise, float* __restrict__ out)
{
    __shared__ _Float16 Bp[4][2][8][64][8];   // 64 KB: quad-buffered B frags
    __shared__ float4   cand[BM][2];          // 2 KB
    __shared__ float4   res[BM];              // 1 KB

    const int tid  = threadIdx.x;
    const int lane = tid & 63;
    const int w    = tid >> 6;          // 0..7
    const int mt   = w >> 1;            // mtile (0..3): rows mt*16..mt*16+15
    const int wnh  = w & 1;             // expert half (0,1)
    const int q    = lane >> 4;
    const int cidx = lane & 15;
    const int row0 = blockIdx.x * BM;

    f32x4  acc[4] = {};                 // [tt: 0,1=gate tiles, 2,3=noise tiles]
    float4 ra[4][2];                    // raw A quad-buffer (slot index always literal)
    half8v af0[2], af1[2];              // converted-A double buffer (literal index)

    // A-frag source row: lane (m=cidx) of this wave's mtile, k-offset q*8
    const float* xr0 = x + (size_t)(row0 + mt * 16 + cidx) * DIMK + q * 8;

    auto issue_B = [&](int c, int buf) {
        #pragma unroll
        for (int ii = 0; ii < 2; ++ii) {          // 16 (p,t) frag blocks / block
            int idx = w * 2 + ii;
            int p = idx >> 3, t = idx & 7;
            const _Float16* g = wsB + ((((size_t)c * 2 + p) * 8 + t) * 64 + lane) * 8;
            async_load16(g, &Bp[buf][p][t][0][0]);
        }
    };

#define ISSUE_A(C, S)                                            \
    {   const float* pa_ = xr0 + (C) * 32;                       \
        ra[S][0] = *(const float4*)(pa_);                        \
        ra[S][1] = *(const float4*)(pa_ + 4);  }

// convert ra[(C)&3] -> af0[P]/af1[P]  (P must be a literal)
#define CONVERT(C, P)                                                        \
    {   _Pragma("unroll")                                                    \
        for (int h = 0; h < 2; ++h) {                                        \
            float4 v = ra[(C) & 3][h];                                       \
            float f0 = v.x * 1024.f, f1 = v.y * 1024.f;                      \
            float f2 = v.z * 1024.f, f3 = v.w * 1024.f;                      \
            _Float16 a0 = (_Float16)f0, a1 = (_Float16)f1;                   \
            _Float16 a2 = (_Float16)f2, a3 = (_Float16)f3;                   \
            af0[P][h * 4 + 0] = a0; af0[P][h * 4 + 1] = a1;                  \
            af0[P][h * 4 + 2] = a2; af0[P][h * 4 + 3] = a3;                  \
            af1[P][h * 4 + 0] = (_Float16)(f0 - (float)a0);                  \
            af1[P][h * 4 + 1] = (_Float16)(f1 - (float)a1);                  \
            af1[P][h * 4 + 2] = (_Float16)(f2 - (float)a2);                  \
            af1[P][h * 4 + 3] = (_Float16)(f3 - (float)a3);                  \
        }                                                                    \
    }

#define FENCE() asm volatile("" ::: "memory")

    // One chunk. Exactly 4 VMEM ops per thread per STEP (2 DMA + 2 float4),
    // batch-contiguous => vmcnt(8) at the top retires batch C while
    // C+1..C+3 stay in flight across the barrier. MFMAs consume af*[C&1]
    // (converted LAST step); convert(C+1) runs after with no MFMA dep.
#define STEP(C, ISS, CV, WN)                                                 \
    {                                                                        \
        asm volatile("s_waitcnt vmcnt(" #WN ")" ::: "memory");               \
        asm volatile("s_barrier" ::: "memory");                              \
        if (ISS) issue_B((C) + 3, ((C) + 3) & 3);                            \
        __builtin_amdgcn_s_setprio(1);                                       \
        _Pragma("unroll")                                                    \
        for (int tt = 0; tt < 4; ++tt) {                                     \
            int ntile = (tt < 2) ? (wnh * 2 + tt) : (4 + wnh * 2 + (tt - 2));\
            half8v b0 = *(const half8v*)&Bp[(C) & 3][0][ntile][lane][0];     \
            half8v b1 = *(const half8v*)&Bp[(C) & 3][1][ntile][lane][0];     \
            acc[tt] = __builtin_amdgcn_mfma_f32_16x16x32_f16(                \
                af0[(C) & 1], b0, acc[tt], 0, 0, 0);                         \
            acc[tt] = __builtin_amdgcn_mfma_f32_16x16x32_f16(                \
                af0[(C) & 1], b1, acc[tt], 0, 0, 0);                         \
            acc[tt] = __builtin_amdgcn_mfma_f32_16x16x32_f16(                \
                af1[(C) & 1], b0, acc[tt], 0, 0, 0);                         \
        }                                                                    \
        __builtin_amdgcn_s_setprio(0);                                       \
        if (ISS) ISSUE_A((C) + 3, ((C) + 3) & 3);                            \
        if (CV)  CONVERT((C) + 1, ((C) + 1) & 1);                            \
    }

    // Prologue: batches 0..2 (fences keep batch issue-order for vmcnt math),
    // then pre-convert chunk 0 (compiler inserts the vmcnt wait for ra[0]).
    issue_B(0, 0);
    ISSUE_A(0, 0);
    FENCE();
    issue_B(1, 1);
    ISSUE_A(1, 1);
    FENCE();
    issue_B(2, 2);
    ISSUE_A(2, 2);
    CONVERT(0, 0);

    #pragma unroll 1
    for (int cb = 0; cb < NCH - 4; cb += 4) {
        STEP(cb + 0, 1, 1, 8)
        STEP(cb + 1, 1, 1, 8)
        STEP(cb + 2, 1, 1, 8)
        STEP(cb + 3, 1, 1, 8)
    }
    // Tail: chunks 60..63 (C=60 issues batch 63; then prefetch tapers off)
    STEP(NCH - 4, 1, 1, 8)
    STEP(NCH - 3, 0, 1, 8)
    STEP(NCH - 2, 0, 1, 4)
    STEP(NCH - 1, 0, 0, 0)

#undef STEP
#undef CONVERT
#undef ISSUE_A
#undef FENCE

    // ---- epilogue ----
    // C/D layout: col = lane&15, row = q*4 + reg. Unscale by 2^-26 (1024*65536).
    const float s = 0x1p-26f;
    {
        float rv[2][4];
        const int rbase = row0 + mt * 16 + q * 4;
        #pragma unroll
        for (int g = 0; g < 2; ++g) {
            int e = wnh * 32 + g * 16 + cidx;
            #pragma unroll
            for (int r = 0; r < 4; ++r) {
                float nz   = noise[(size_t)(rbase + r) * NEXP + e];
                float gate = acc[g][r] * s;
                float nv   = acc[g + 2][r] * s;
                float sp   = fmaxf(nv, 0.f) + log1pf(expf(-fabsf(nv)));
                rv[g][r]   = gate + nz * (sp + 0.01f);
            }
        }
        #pragma unroll
        for (int r = 0; r < 4; ++r) {
            int e0 = wnh * 32 + cidx, e1 = e0 + 16;
            float v1, v2; int i1, i2;
            float a = rv[0][r], b = rv[1][r];
            if (a >= b) { v1 = a; i1 = e0; v2 = b; i2 = e1; }   // e0<e1: tie ok
            else        { v1 = b; i1 = e1; v2 = a; i2 = e0; }
            #pragma unroll
            for (int m = 1; m <= 8; m <<= 1) {    // butterfly across the 16-lane quad
                float b1 = __shfl_xor(v1, m); int ib1 = __shfl_xor(i1, m);
                float b2 = __shfl_xor(v2, m); int ib2 = __shfl_xor(i2, m);
                if (gt_pair(b1, ib1, v1, i1)) {
                    float o1 = v1; int oi1 = i1;
                    v1 = b1; i1 = ib1;
                    if (gt_pair(b2, ib2, o1, oi1)) { v2 = b2; i2 = ib2; }
                    else                           { v2 = o1; i2 = oi1; }
                } else if (gt_pair(b1, ib1, v2, i2)) {
                    v2 = b1; i2 = ib1;
                }
            }
            if (cidx == 0) {
                int rowb = mt * 16 + q * 4 + r;
                cand[rowb][wnh] = make_float4(v1, __int_as_float(i1),
                                              v2, __int_as_float(i2));
            }
        }
    }
    __syncthreads();

    if (tid < BM) {   // merge the two expert-half candidates, softmax
        float4 c0 = cand[tid][0], c1 = cand[tid][1];
        float mv1 = c0.x; int mi1 = __float_as_int(c0.y);
        float mv2 = c0.z; int mi2 = __float_as_int(c0.w);
        float b1 = c1.x;  int ib1 = __float_as_int(c1.y);
        float b2 = c1.z;  int ib2 = __float_as_int(c1.w);
        if (gt_pair(b1, ib1, mv1, mi1)) {
            float o1 = mv1; int oi1 = mi1;
            mv1 = b1; mi1 = ib1;
            if (gt_pair(b2, ib2, o1, oi1)) { mv2 = b2; mi2 = ib2; }
            else                           { mv2 = o1; mi2 = oi1; }
        } else if (gt_pair(b1, ib1, mv2, mi2)) {
            mv2 = b1; mi2 = ib1;
        }
        float t  = expf(mv2 - mv1);     // <= 1
        float g1 = 1.f / (1.f + t);
        res[tid] = make_float4(g1, __int_as_float(mi1),
                               t * g1, __int_as_float(mi2));
    }
    __syncthreads();

    {   // write full 64x64 out tile: thread -> row tid>>3, 8-col segment
        int rr  = tid >> 3;          // 0..63
        int seg = tid & 7;           // 0..7
        float4 rv = res[rr];
        float g1 = rv.x, g2 = rv.z;
        int   j1 = __float_as_int(rv.y), j2 = __float_as_int(rv.w);
        float* op = out + (size_t)(row0 + rr) * NEXP + seg * 8;
        #pragma unroll
        for (int qq = 0; qq < 2; ++qq) {
            int e0 = seg * 8 + qq * 4;
            float4 o;
            o.x = (e0 + 0 == j1) ? g1 : ((e0 + 0 == j2) ? g2 : 0.f);
            o.y = (e0 + 1 == j1) ? g1 : ((e0 + 1 == j2) ? g2 : 0.f);
            o.z = (e0 + 2 == j1) ? g1 : ((e0 + 2 == j2) ? g2 : 0.f);
            o.w = (e0 + 3 == j1) ? g1 : ((e0 + 3 == j2) ? g2 : 0.f);
            *(float4*)(op + qq * 4) = o;
        }
    }
}

extern "C" void kernel_launch(void* const* d_in, const int* in_sizes, int n_in,
                              void* d_out, int out_size, void* d_ws, size_t ws_size,
                              hipStream_t stream) {
    const float* x     = (const float*)d_in[0];
    const float* wg    = (const float*)d_in[1];
    const float* wn    = (const float*)d_in[2];
    const float* noise = (const float*)d_in[3];
    float* out = (float*)d_out;
    _Float16* wsB = (_Float16*)d_ws;   // needs 64*2*8*1KB = 1 MB

    presplit_kernel<<<dim3(128), 256, 0, stream>>>(wg, wn, wsB);

    const int Brows = in_sizes[0] / DIMK;          // 32768
    dim3 grid(Brows / BM);                         // 512 blocks -> 2/CU, 16 waves/CU
    routing_mfma<<<grid, 512, 0, stream>>>(x, wsB, noise, out);
}